// Round 1
// baseline (133.229 us; speedup 1.0000x reference)
//
#include <hip/hip_runtime.h>
#include <hip/hip_bf16.h>

#define EE 256
#define HIDD 150
#define HP 160
#define NN 384
#define NB 2
#define JTILE 64
#define NJT 6

typedef float f32x4 __attribute__((ext_vector_type(4)));
typedef short bf16x8 __attribute__((ext_vector_type(8)));

__device__ __forceinline__ short bf16r(float f) {
  unsigned u = __builtin_bit_cast(unsigned, f);
  u = (u + 0x7fffu + ((u >> 16) & 1u)) >> 16;
  return (short)u;
}

// ---- pack W1c (rows 512..767 of W1) and W2 into MFMA B-fragment order ----
// frag k-convention (both A and B): row/col = lane&15, k = (lane>>4)*8 + e
// w1p[((k8*10 + t)*64 + lane)*8 + e] = W1c[k8*32 + (lane>>4)*8 + e][t*16 + (lane&15)]
__global__ void pack_weights(const float* __restrict__ W1, const float* __restrict__ W2,
                             short* __restrict__ w1p, short* __restrict__ w2p) {
  int idx = blockIdx.x * blockDim.x + threadIdx.x;
  if (idx < 40960) {
    int e = idx & 7, lane = (idx >> 3) & 63, tile = idx >> 9;
    int t = tile % 10, k8 = tile / 10;
    int eg = k8 * 32 + ((lane >> 4) << 3) + e;
    int h = t * 16 + (lane & 15);
    w1p[idx] = bf16r((h < HIDD) ? W1[(512 + eg) * HIDD + h] : 0.f);
  }
  int idx2 = idx - 40960;
  if (idx2 >= 0 && idx2 < 25600) {
    int e = idx2 & 7, lane = (idx2 >> 3) & 63, tile = idx2 >> 9;
    int t = tile % 10, k5 = tile / 10;
    int kk = k5 * 32 + ((lane >> 4) << 3) + e;
    int h = t * 16 + (lane & 15);
    w2p[idx2] = bf16r((kk < HIDD && h < HIDD) ? W2[kk * HIDD + h] : 0.f);
  }
}

// ---- U[b,n,h] = x@W1a + b1 ; V[b,n,h] = x@W1b  (fp32, padded to HP) ----
__global__ void compute_uv(const float* __restrict__ X, const float* __restrict__ W1,
                           const float* __restrict__ b1,
                           float* __restrict__ U, float* __restrict__ V) {
  int bi = blockIdx.x;
  __shared__ float xs[EE];
  for (int e = threadIdx.x; e < EE; e += blockDim.x) xs[e] = X[bi * EE + e];
  __syncthreads();
  int h = threadIdx.x;
  if (h < HP) {
    float u = 0.f, v = 0.f;
    if (h < HIDD) {
      for (int e = 0; e < EE; e++) {
        u = fmaf(xs[e], W1[e * HIDD + h], u);
        v = fmaf(xs[e], W1[(EE + e) * HIDD + h], v);
      }
      u += b1[h];
    }
    U[bi * HP + h] = u;
    V[bi * HP + h] = v;
  }
}

// ---- main: one block per (b, i, j-tile of 64); 4 waves, wave w owns j rows [w*16, w*16+16) ----
__global__ __launch_bounds__(256) void pair_main(
    const float* __restrict__ X, const float* __restrict__ M,
    const float* __restrict__ b2, const float* __restrict__ W3, const float* __restrict__ b3,
    const float* __restrict__ U, const float* __restrict__ V,
    const short* __restrict__ w1p, const short* __restrict__ w2p,
    float* __restrict__ out) {
  int bx = blockIdx.x;
  int jt = bx % NJT;
  int i = (bx / NJT) % NN;
  int b = bx / (NJT * NN);

  int tid = threadIdx.x;
  int lane = tid & 63;
  int w = tid >> 6;
  int hcol = lane & 15;
  int rgrp = lane >> 4;

  __shared__ float xs[EE];
  __shared__ float Uf[HP];
  __shared__ float b2s[HP];
  __shared__ float W3s[HP];
  __shared__ float ms[JTILE];
  __shared__ short h1s[4][16 * 192];  // per-wave 16 rows x 384B (swizzle-safe stride)

  const float* xi = X + (b * NN + i) * EE;
  for (int e = tid; e < EE; e += 256) xs[e] = xi[e];
  if (tid < HP) {
    Uf[tid] = U[(b * NN + i) * HP + tid];
    b2s[tid] = (tid < HIDD) ? b2[tid] : 0.f;
    W3s[tid] = (tid < HIDD) ? W3[tid] : 0.f;
  }
  if (tid < JTILE) ms[tid] = M[b * NN + jt * JTILE + tid];
  __syncthreads();

  int jA = jt * JTILE + w * 16 + hcol;     // row of X this lane loads for A-frags
  int jO0 = jt * JTILE + w * 16 + rgrp * 4;  // this lane's 4 output j rows (C/D layout)
  const float* xj = X + (b * NN + jA) * EE;

  // GEMM1 accumulators, init with U[i,h] + V[j,h]
  f32x4 acc[10];
  #pragma unroll
  for (int t = 0; t < 10; t++) {
    int h = t * 16 + hcol;
    float uf = Uf[h];
    const float* vp = V + (b * NN + jO0) * HP + h;
    acc[t][0] = uf + vp[0];
    acc[t][1] = uf + vp[HP];
    acc[t][2] = uf + vp[2 * HP];
    acc[t][3] = uf + vp[3 * HP];
  }

  // GEMM1: C1[j,h] += sum_e (x_j[e]*x_i[e]) * W1c[e,h]
  for (int k8 = 0; k8 < 8; k8++) {
    int e0 = k8 * 32 + rgrp * 8;
    float4 a0 = *reinterpret_cast<const float4*>(xj + e0);
    float4 a1 = *reinterpret_cast<const float4*>(xj + e0 + 4);
    float4 s0 = *reinterpret_cast<const float4*>(xs + e0);
    float4 s1 = *reinterpret_cast<const float4*>(xs + e0 + 4);
    bf16x8 af;
    af[0] = bf16r(a0.x * s0.x); af[1] = bf16r(a0.y * s0.y);
    af[2] = bf16r(a0.z * s0.z); af[3] = bf16r(a0.w * s0.w);
    af[4] = bf16r(a1.x * s1.x); af[5] = bf16r(a1.y * s1.y);
    af[6] = bf16r(a1.z * s1.z); af[7] = bf16r(a1.w * s1.w);
    const short* wp = w1p + k8 * 5120 + lane * 8;
    #pragma unroll
    for (int t = 0; t < 10; t++) {
      bf16x8 bf = *reinterpret_cast<const bf16x8*>(wp + t * 512);
      acc[t] = __builtin_amdgcn_mfma_f32_16x16x32_bf16(af, bf, acc[t], 0, 0, 0);
    }
  }

  // relu -> bf16 -> wave-private LDS (XOR swizzle on bits 4..6, bijective with 384B stride)
  char* hb = reinterpret_cast<char*>(&h1s[w][0]);
  #pragma unroll
  for (int t = 0; t < 10; t++) {
    #pragma unroll
    for (int r = 0; r < 4; r++) {
      int jl = rgrp * 4 + r;
      int byteoff = jl * 384 + (t * 16 + hcol) * 2;
      byteoff ^= (jl & 7) << 4;
      *reinterpret_cast<short*>(hb + byteoff) = bf16r(fmaxf(acc[t][r], 0.f));
    }
  }

  // GEMM2 accumulators, init with b2
  #pragma unroll
  for (int t = 0; t < 10; t++) {
    float bb = b2s[t * 16 + hcol];
    acc[t][0] = bb; acc[t][1] = bb; acc[t][2] = bb; acc[t][3] = bb;
  }
  for (int k5 = 0; k5 < 5; k5++) {
    int byteoff = hcol * 384 + (k5 * 32 + rgrp * 8) * 2;
    byteoff ^= (hcol & 7) << 4;
    bf16x8 af = *reinterpret_cast<const bf16x8*>(hb + byteoff);
    const short* wp = w2p + k5 * 5120 + lane * 8;
    #pragma unroll
    for (int t = 0; t < 10; t++) {
      bf16x8 bf = *reinterpret_cast<const bf16x8*>(wp + t * 512);
      acc[t] = __builtin_amdgcn_mfma_f32_16x16x32_bf16(af, bf, acc[t], 0, 0, 0);
    }
  }

  // layer 3: s[j] = sum_h relu(C2+b2)[j,h] * W3[h]  (b2 already in acc)
  float pr0 = 0.f, pr1 = 0.f, pr2 = 0.f, pr3 = 0.f;
  #pragma unroll
  for (int t = 0; t < 10; t++) {
    float w3 = W3s[t * 16 + hcol];
    pr0 = fmaf(fmaxf(acc[t][0], 0.f), w3, pr0);
    pr1 = fmaf(fmaxf(acc[t][1], 0.f), w3, pr1);
    pr2 = fmaf(fmaxf(acc[t][2], 0.f), w3, pr2);
    pr3 = fmaf(fmaxf(acc[t][3], 0.f), w3, pr3);
  }
  #pragma unroll
  for (int mk = 1; mk <= 8; mk <<= 1) {
    pr0 += __shfl_xor(pr0, mk);
    pr1 += __shfl_xor(pr1, mk);
    pr2 += __shfl_xor(pr2, mk);
    pr3 += __shfl_xor(pr3, mk);
  }

  if (hcol == 0) {
    float mi = M[b * NN + i];
    float bb3 = b3[0];
    int jl0 = w * 16 + rgrp * 4;
    float4 o;
    o.x = (mi + ms[jl0 + 0] + pr0 + bb3) * (1.f / 3.f);
    o.y = (mi + ms[jl0 + 1] + pr1 + bb3) * (1.f / 3.f);
    o.z = (mi + ms[jl0 + 2] + pr2 + bb3) * (1.f / 3.f);
    o.w = (mi + ms[jl0 + 3] + pr3 + bb3) * (1.f / 3.f);
    *reinterpret_cast<float4*>(out + (b * NN + i) * NN + jt * JTILE + jl0) = o;
  }
}

extern "C" void kernel_launch(void* const* d_in, const int* in_sizes, int n_in,
                              void* d_out, int out_size, void* d_ws, size_t ws_size,
                              hipStream_t stream) {
  const float* X  = (const float*)d_in[0];
  const float* M  = (const float*)d_in[1];
  const float* W1 = (const float*)d_in[2];
  const float* b1 = (const float*)d_in[3];
  const float* W2 = (const float*)d_in[4];
  const float* b2 = (const float*)d_in[5];
  const float* W3 = (const float*)d_in[6];
  const float* b3 = (const float*)d_in[7];
  float* out = (float*)d_out;

  float* U = (float*)d_ws;                       // 768*160 f32
  float* V = U + NB * NN * HP;                   // 768*160 f32
  short* w1p = (short*)(V + NB * NN * HP);       // 40960 bf16
  short* w2p = w1p + 40960;                      // 25600 bf16

  hipLaunchKernelGGL(pack_weights, dim3(260), dim3(256), 0, stream, W1, W2, w1p, w2p);
  hipLaunchKernelGGL(compute_uv, dim3(NB * NN), dim3(192), 0, stream, X, W1, b1, U, V);
  hipLaunchKernelGGL(pair_main, dim3(NB * NN * NJT), dim3(256), 0, stream,
                     X, M, b2, W3, b3, U, V, w1p, w2p, out);
}